// Round 10
// baseline (56.914 us; speedup 1.0000x reference)
//
#include <hip/hip_runtime.h>
#include <cstdint>
#include <cstddef>

typedef __attribute__((ext_vector_type(8))) short short8;
typedef __attribute__((ext_vector_type(4))) unsigned short ushort4_t;
typedef __attribute__((ext_vector_type(16))) float f32x16;

#define NF 40
#define NK 780           // 40*39/2 pairs
#define BT 64            // batch rows per block
#define THREADS 1024     // 16 waves
#define KSPLIT 2         // -> grid 256 = 1 block/CU on all CUs

__device__ __forceinline__ unsigned short f2bf(float f) {
    unsigned int u = __float_as_uint(f);
    u = (u + 0x7fffu + ((u >> 16) & 1u)) >> 16;
    return (unsigned short)u;
}
__device__ __forceinline__ float bf2f(unsigned short x) {
    return __uint_as_float(((unsigned int)x) << 16);
}

// wfrag[k][half][l][t] = bf16( W[k][ e = l&31 ][ 16*half + 8*(l>>5) + t ] )
__global__ __launch_bounds__(128) void wprep_kernel(const float* __restrict__ W,
                                                    unsigned short* __restrict__ wfrag) {
    const int k = blockIdx.x, t = threadIdx.x;
    const int half = t >> 6, l = t & 63;
    const int e = l & 31;
    const int f0 = 16 * half + 8 * (l >> 5);
    const float* src = W + (size_t)k * 1024 + e * 32 + f0;
    const float4 x0 = *(const float4*)src;
    const float4 x1 = *(const float4*)(src + 4);
    short8 v;
    v[0] = (short)f2bf(x0.x); v[1] = (short)f2bf(x0.y);
    v[2] = (short)f2bf(x0.z); v[3] = (short)f2bf(x0.w);
    v[4] = (short)f2bf(x1.x); v[5] = (short)f2bf(x1.y);
    v[6] = (short)f2bf(x1.z); v[7] = (short)f2bf(x1.w);
    *(short8*)(wfrag + (size_t)k * 1024 + half * 512 + l * 8) = v;
}

// --- forced-pipeline primitives -------------------------------------------------
__device__ __forceinline__ void ld_w4(short8& r0, short8& r1, short8& r2, short8& r3,
                                      const char* addr) {
    asm volatile("global_load_dwordx4 %0, %4, off\n\t"
                 "global_load_dwordx4 %1, %4, off offset:1024\n\t"
                 "global_load_dwordx4 %2, %4, off offset:2048\n\t"
                 "global_load_dwordx4 %3, %4, off offset:3072"
                 : "=&v"(r0), "=&v"(r1), "=&v"(r2), "=&v"(r3)
                 : "v"(addr));
}
#define WAITP() do { asm volatile("s_waitcnt vmcnt(4)" ::: "memory"); \
                     __builtin_amdgcn_sched_barrier(0); } while (0)
#define WAIT0() do { asm volatile("s_waitcnt vmcnt(0)" ::: "memory"); \
                     __builtin_amdgcn_sched_barrier(0); } while (0)

#define LOADW2(R0, R1, R2, R3, KB)                                                      \
    {                                                                                   \
        const int kbc = (KB) > 778 ? 778 : (KB);                                        \
        ld_w4(R0, R1, R2, R3, wbase + ((size_t)kbc << 11));                             \
    }

// embT granule (field, g): g = (b + 64*fq) ^ (field&7); holds bf16 of
// emb[b0+b][field][8*fq..8*fq+7]. 4096 B per field.

#define RELOAD_VI()                                                                     \
    {                                                                                   \
        const int i7 = ii & 7;                                                          \
        const char* ibase = embT + (ii << 12) + eoff;                                   \
        const ushort4_t a0_ = *(const ushort4_t*)(ibase + (((b32      ) ^ i7) << 4));   \
        const ushort4_t a1_ = *(const ushort4_t*)(ibase + (((b32 +  64) ^ i7) << 4));   \
        const ushort4_t a2_ = *(const ushort4_t*)(ibase + (((b32 + 128) ^ i7) << 4));   \
        const ushort4_t a3_ = *(const ushort4_t*)(ibase + (((b32 + 192) ^ i7) << 4));   \
        const ushort4_t b0_ = *(const ushort4_t*)(ibase + (((b32 +  32) ^ i7) << 4));   \
        const ushort4_t b1_ = *(const ushort4_t*)(ibase + (((b32 +  96) ^ i7) << 4));   \
        const ushort4_t b2_ = *(const ushort4_t*)(ibase + (((b32 + 160) ^ i7) << 4));   \
        const ushort4_t b3_ = *(const ushort4_t*)(ibase + (((b32 + 224) ^ i7) << 4));   \
        uA0 = bf2f(a0_[0]); uA1 = bf2f(a0_[1]); uA2  = bf2f(a0_[2]); uA3  = bf2f(a0_[3]); \
        uA4 = bf2f(a1_[0]); uA5 = bf2f(a1_[1]); uA6  = bf2f(a1_[2]); uA7  = bf2f(a1_[3]); \
        uA8 = bf2f(a2_[0]); uA9 = bf2f(a2_[1]); uA10 = bf2f(a2_[2]); uA11 = bf2f(a2_[3]); \
        uA12 = bf2f(a3_[0]); uA13 = bf2f(a3_[1]); uA14 = bf2f(a3_[2]); uA15 = bf2f(a3_[3]); \
        uB0 = bf2f(b0_[0]); uB1 = bf2f(b0_[1]); uB2  = bf2f(b0_[2]); uB3  = bf2f(b0_[3]); \
        uB4 = bf2f(b1_[0]); uB5 = bf2f(b1_[1]); uB6  = bf2f(b1_[2]); uB7  = bf2f(b1_[3]); \
        uB8 = bf2f(b2_[0]); uB9 = bf2f(b2_[1]); uB10 = bf2f(b2_[2]); uB11 = bf2f(b2_[3]); \
        uB12 = bf2f(b3_[0]); uB13 = bf2f(b3_[1]); uB14 = bf2f(b3_[2]); uB15 = bf2f(b3_[3]); \
    }

#define DOT16(T, V0, V1, V2, V3, V4, V5, V6, V7, V8, V9, V10, V11, V12, V13, V14, V15, P) \
    {                                                                                   \
        float d0 = T[0] * V0;                                                           \
        d0 = __builtin_fmaf(T[1], V1, d0);                                              \
        d0 = __builtin_fmaf(T[2], V2, d0);                                              \
        d0 = __builtin_fmaf(T[3], V3, d0);                                              \
        float d1 = T[4] * V4;                                                           \
        d1 = __builtin_fmaf(T[5], V5, d1);                                              \
        d1 = __builtin_fmaf(T[6], V6, d1);                                              \
        d1 = __builtin_fmaf(T[7], V7, d1);                                              \
        float d2 = T[8] * V8;                                                           \
        d2 = __builtin_fmaf(T[9], V9, d2);                                              \
        d2 = __builtin_fmaf(T[10], V10, d2);                                            \
        d2 = __builtin_fmaf(T[11], V11, d2);                                            \
        float d3 = T[12] * V12;                                                         \
        d3 = __builtin_fmaf(T[13], V13, d3);                                            \
        d3 = __builtin_fmaf(T[14], V14, d3);                                            \
        d3 = __builtin_fmaf(T[15], V15, d3);                                            \
        P = (d0 + d1) + (d2 + d3);                                                      \
        P += __shfl_xor(P, 32);                                                         \
    }

// one k x BOTH row-halves: 4 ds_read_b128 + 4 MFMA + 2 dot-epilogues
#define KSTEP(A0, A1, OA, OB)                                                           \
    {                                                                                   \
        const int j7 = jj & 7;                                                          \
        const char* jbase = embT + (jj << 12);                                          \
        const short8 vjA0 = *(const short8*)(jbase + (((b32 +       fh0) ^ j7) << 4));  \
        const short8 vjA1 = *(const short8*)(jbase + (((b32 + 128 + fh0) ^ j7) << 4));  \
        const short8 vjB0 = *(const short8*)(jbase + (((b32 + 32  + fh0) ^ j7) << 4));  \
        const short8 vjB1 = *(const short8*)(jbase + (((b32 + 160 + fh0) ^ j7) << 4));  \
        f32x16 tA = __builtin_amdgcn_mfma_f32_32x32x16_bf16(A0, vjA0, zacc, 0, 0, 0);   \
        tA = __builtin_amdgcn_mfma_f32_32x32x16_bf16(A1, vjA1, tA, 0, 0, 0);            \
        f32x16 tB = __builtin_amdgcn_mfma_f32_32x32x16_bf16(A0, vjB0, zacc, 0, 0, 0);   \
        tB = __builtin_amdgcn_mfma_f32_32x32x16_bf16(A1, vjB1, tB, 0, 0, 0);            \
        DOT16(tA, uA0, uA1, uA2, uA3, uA4, uA5, uA6, uA7,                               \
                  uA8, uA9, uA10, uA11, uA12, uA13, uA14, uA15, OA);                    \
        DOT16(tB, uB0, uB1, uB2, uB3, uB4, uB5, uB6, uB7,                               \
                  uB8, uB9, uB10, uB11, uB12, uB13, uB14, uB15, OB);                    \
        ++jj;                                                                           \
        if (jj == NF) { ++ii; jj = ii + 1; RELOAD_VI(); }                               \
    }

__global__ __launch_bounds__(THREADS, 4) void bil_kernel(const float* __restrict__ emb,
                                                         const unsigned short* __restrict__ wfrag,
                                                         float* __restrict__ out) {
    __shared__ __align__(16) char embT[NF * 4096];   // 163840 B = full LDS pool

    const int tid = threadIdx.x;
    const int btile = blockIdx.x >> 1;
    const int khalf = blockIdx.x & 1;
    const int b0 = btile * BT;

    // --- Stage 64-row tile: coalesced 32B global reads, swizzled LDS writes ---
    for (int u = tid; u < BT * 160; u += THREADS) {
        const int bb = u / 160;
        const int t = u - 160 * bb;
        const int field = t >> 2;
        const int fq = t & 3;
        const float* src = emb + (size_t)(b0 + bb) * (NF * 32) + field * 32 + 8 * fq;
        const float4 x0 = *(const float4*)src;
        const float4 x1 = *(const float4*)(src + 4);
        short8 v;
        v[0] = (short)f2bf(x0.x); v[1] = (short)f2bf(x0.y);
        v[2] = (short)f2bf(x0.z); v[3] = (short)f2bf(x0.w);
        v[4] = (short)f2bf(x1.x); v[5] = (short)f2bf(x1.y);
        v[6] = (short)f2bf(x1.z); v[7] = (short)f2bf(x1.w);
        const int g = (bb + 64 * fq) ^ (field & 7);
        *(short8*)(embT + field * 4096 + g * 16) = v;
    }
    __syncthreads();

    const int ww = tid >> 6;            // wave 0..15
    const int l = tid & 63;
    const int b32 = l & 31;
    const int h32 = l >> 5;
    const int fh0 = 64 * h32;           // vj granule offset within an f-half
    const int eoff = 8 * h32;           // byte offset within vi granule

    const f32x16 zacc = {};

    // pp-range (1 pp = 2 k) per wave within this block's k-half; start multiple of 2 pp
    // (=> k multiple of 4, 16B-aligned stores). Last wave absorbs the odd pp.
    const int ppbase = khalf * 195;
    const int ps = ppbase + 2 * ((195 * ww) >> 5);
    const int pe = ppbase + ((ww == 15) ? 195 : 2 * ((195 * (ww + 1)) >> 5));

    int ii = 0, jj;                     // (i,j) for k = 2*ps, i-major triu order
    {
        int kk = 2 * ps, len = 39;
        while (kk >= len) { kk -= len; ++ii; --len; }
        jj = ii + 1 + kk;
    }

    float uA0, uA1, uA2, uA3, uA4, uA5, uA6, uA7;
    float uA8, uA9, uA10, uA11, uA12, uA13, uA14, uA15;
    float uB0, uB1, uB2, uB3, uB4, uB5, uB6, uB7;
    float uB8, uB9, uB10, uB11, uB12, uB13, uB14, uB15;
    RELOAD_VI();

    const char* wbase = (const char*)wfrag + l * 16;

    short8 aw0, aw1, aw2, aw3;          // bank A (holds current 2-k group)
    short8 bw0, bw1, bw2, bw3;          // bank B
    LOADW2(aw0, aw1, aw2, aw3, 2 * ps);

    const size_t orowoff = (size_t)(b0 + 32 * h32 + b32) * NK;  // lane's output row

    int pp = ps;
    for (; pp + 4 <= pe; pp += 4) {     // 8-k superblock, 32B/lane store
        const int kcur = 2 * pp;
        float oA0, oA1, oA2, oA3, oA4, oA5, oA6, oA7;
        float oB0, oB1, oB2, oB3, oB4, oB5, oB6, oB7;
        LOADW2(bw0, bw1, bw2, bw3, kcur + 2);
        WAITP();
        KSTEP(aw0, aw1, oA0, oB0);  KSTEP(aw2, aw3, oA1, oB1);
        LOADW2(aw0, aw1, aw2, aw3, kcur + 4);
        WAITP();
        KSTEP(bw0, bw1, oA2, oB2);  KSTEP(bw2, bw3, oA3, oB3);
        LOADW2(bw0, bw1, bw2, bw3, kcur + 6);
        WAITP();
        KSTEP(aw0, aw1, oA4, oB4);  KSTEP(aw2, aw3, oA5, oB5);
        LOADW2(aw0, aw1, aw2, aw3, kcur + 8);
        WAITP();
        KSTEP(bw0, bw1, oA6, oB6);  KSTEP(bw2, bw3, oA7, oB7);
        float4 s0, s1;
        if (h32 == 0) { s0.x = oA0; s0.y = oA1; s0.z = oA2; s0.w = oA3;
                        s1.x = oA4; s1.y = oA5; s1.z = oA6; s1.w = oA7; }
        else          { s0.x = oB0; s0.y = oB1; s0.z = oB2; s0.w = oB3;
                        s1.x = oB4; s1.y = oB5; s1.z = oB6; s1.w = oB7; }
        float* orow = out + orowoff + kcur;
        *(float4*)orow = s0;
        *(float4*)(orow + 4) = s1;
    }
    if (pp + 2 <= pe) {                 // 4-k tail chunk, 16B store (k mult of 4)
        const int kcur = 2 * pp;
        float oA0, oA1, oA2, oA3, oB0, oB1, oB2, oB3;
        LOADW2(bw0, bw1, bw2, bw3, kcur + 2);
        WAITP();
        KSTEP(aw0, aw1, oA0, oB0);  KSTEP(aw2, aw3, oA1, oB1);
        LOADW2(aw0, aw1, aw2, aw3, kcur + 4);
        WAITP();
        KSTEP(bw0, bw1, oA2, oB2);  KSTEP(bw2, bw3, oA3, oB3);
        float4 s0;
        if (h32 == 0) { s0.x = oA0; s0.y = oA1; s0.z = oA2; s0.w = oA3; }
        else          { s0.x = oB0; s0.y = oB1; s0.z = oB2; s0.w = oB3; }
        *(float4*)(out + orowoff + kcur) = s0;
        pp += 2;
    }
    if (pp < pe) {                      // 2-k tail, 8B store; bank A holds this group
        const int kcur = 2 * pp;
        float oA0, oA1, oB0, oB1;
        WAIT0();
        KSTEP(aw0, aw1, oA0, oB0);  KSTEP(aw2, aw3, oA1, oB1);
        float2 s0;
        if (h32 == 0) { s0.x = oA0; s0.y = oA1; }
        else          { s0.x = oB0; s0.y = oB1; }
        *(float2*)(out + orowoff + kcur) = s0;
    }
}

extern "C" void kernel_launch(void* const* d_in, const int* in_sizes, int n_in,
                              void* d_out, int out_size, void* d_ws, size_t ws_size,
                              hipStream_t stream) {
    const float* emb = (const float*)d_in[0];
    const float* W   = (const float*)d_in[1];
    float* out = (float*)d_out;
    unsigned short* wfrag = (unsigned short*)d_ws;   // 780*2048 B = 1.6 MB scratch

    wprep_kernel<<<dim3(NK), dim3(128), 0, stream>>>(W, wfrag);
    bil_kernel<<<dim3((8192 / BT) * KSPLIT), dim3(THREADS), 0, stream>>>(emb, wfrag, out);
}